// Round 11
// baseline (115.922 us; speedup 1.0000x reference)
//
#include <hip/hip_runtime.h>
#include <hip/hip_bf16.h>

#define BB 16
#define NQ 64
#define NK 512
#define HD 256   // H = QS = KS = VD = 256

typedef __attribute__((ext_vector_type(8))) short short8;
typedef __attribute__((ext_vector_type(4))) float f32x4;

__device__ __forceinline__ ushort bf16_rne(float v) {
    unsigned u = __float_as_uint(v);
    return (ushort)((u + 0x7FFFu + ((u >> 16) & 1u)) >> 16);
}
__device__ __forceinline__ float bf16_to_f(ushort h) {
    return __uint_as_float(((unsigned)h) << 16);
}

// ---------------------------------------------------------------------------
// W-only conversion (tiny): W fp32 [k][n] -> hi/lo bf16 TRANSPOSED [n][k].
// ---------------------------------------------------------------------------
__global__ __launch_bounds__(256) void wconv(
    const float* __restrict__ wq, const float* __restrict__ wk,
    ushort* __restrict__ wqh, ushort* __restrict__ wql,
    ushort* __restrict__ wkh, ushort* __restrict__ wkl)
{
    int widx = blockIdx.x * 256 + threadIdx.x;     // 0..32767
    const float* W; ushort *wh, *wl;
    if (widx < 16384) { W = wq; wh = wqh; wl = wql; }
    else { W = wk; wh = wkh; wl = wkl; widx -= 16384; }
    int n  = widx >> 6;
    int k4 = (widx & 63) * 4;
    ushort hh[4], ll[4];
    #pragma unroll
    for (int c = 0; c < 4; ++c) {
        float v = W[(k4 + c) * 256 + n];
        hh[c] = bf16_rne(v);
        ll[c] = bf16_rne(v - bf16_to_f(hh[c]));
    }
    *(ushort4*)&wh[n * 256 + k4] = make_ushort4(hh[0], hh[1], hh[2], hh[3]);
    *(ushort4*)&wl[n * 256 + k4] = make_ushort4(ll[0], ll[1], ll[2], ll[3]);
}

// ---------------------------------------------------------------------------
// Projection GEMM with FUSED A-conversion (as R10): tile 64x64, BK=64,
// 576 blocks, XOR-swizzled LDS, product-major MFMA.
// ---------------------------------------------------------------------------
__global__ __launch_bounds__(256, 2) void proj_fused(
    const float* __restrict__ queries, const float* __restrict__ keys,
    const ushort* __restrict__ wqh, const ushort* __restrict__ wql,
    const ushort* __restrict__ wkh, const ushort* __restrict__ wkl,
    float* __restrict__ qp, float* __restrict__ kp, float scale)
{
    __shared__ ushort AsH[64 * 64], AsL[64 * 64];
    __shared__ ushort BsH[64 * 64], BsL[64 * 64];

    const float* A; const ushort *Bh, *Bl; float* C; int rows0;
    const int bx = blockIdx.x;
    if (bx < 16) { A = queries; Bh = wqh; Bl = wql; C = qp; rows0 = bx * 64; }
    else         { A = keys;    Bh = wkh; Bl = wkl; C = kp; rows0 = (bx - 16) * 64; }
    const int cols0 = blockIdx.y * 64;

    const int t = threadIdx.x, lane = t & 63, wave = t >> 6;
    const int quad = lane >> 4, l15 = lane & 15;
    const int sr  = t >> 2;
    const int sc2 = (t & 3) * 2;

    f32x4 acc[4];
    #pragma unroll
    for (int j = 0; j < 4; ++j) acc[j] = (f32x4){0.f, 0.f, 0.f, 0.f};

    for (int k0 = 0; k0 < 256; k0 += 64) {
        const float* arow = &A[(size_t)(rows0 + sr) * 256 + k0 + sc2 * 8];
        float4 a0 = *(const float4*)&arow[0];
        float4 a1 = *(const float4*)&arow[4];
        float4 a2 = *(const float4*)&arow[8];
        float4 a3 = *(const float4*)&arow[12];
        const ushort* bhp = &Bh[(size_t)(cols0 + sr) * 256 + k0 + sc2 * 8];
        const ushort* blp = &Bl[(size_t)(cols0 + sr) * 256 + k0 + sc2 * 8];
        short8 b0h = *(const short8*)&bhp[0];
        short8 b1h = *(const short8*)&bhp[8];
        short8 b0l = *(const short8*)&blp[0];
        short8 b1l = *(const short8*)&blp[8];

        __syncthreads();

        float av[16] = {a0.x, a0.y, a0.z, a0.w, a1.x, a1.y, a1.z, a1.w,
                        a2.x, a2.y, a2.z, a2.w, a3.x, a3.y, a3.z, a3.w};
        short8 ah0, ah1, al0, al1;
        #pragma unroll
        for (int e = 0; e < 8; ++e) {
            ushort h0 = bf16_rne(av[e]);
            ushort h1 = bf16_rne(av[8 + e]);
            ah0[e] = (short)h0;
            ah1[e] = (short)h1;
            al0[e] = (short)bf16_rne(av[e] - bf16_to_f(h0));
            al1[e] = (short)bf16_rne(av[8 + e] - bf16_to_f(h1));
        }
        {
            int s0 = sr * 8 + ((sc2 + 0) ^ (sr & 7));
            int s1 = sr * 8 + ((sc2 + 1) ^ (sr & 7));
            *(short8*)&AsH[s0 * 8] = ah0;
            *(short8*)&AsH[s1 * 8] = ah1;
            *(short8*)&AsL[s0 * 8] = al0;
            *(short8*)&AsL[s1 * 8] = al1;
            *(short8*)&BsH[s0 * 8] = b0h;
            *(short8*)&BsH[s1 * 8] = b1h;
            *(short8*)&BsL[s0 * 8] = b0l;
            *(short8*)&BsL[s1 * 8] = b1l;
        }
        __syncthreads();

        #pragma unroll
        for (int ks = 0; ks < 2; ++ks) {
            const int c = ks * 4 + quad;
            short8 aH, aL, bH[4], bL[4];
            {
                int r = wave * 16 + l15;
                int slot = r * 8 + (c ^ (r & 7));
                aH = *(const short8*)&AsH[slot * 8];
                aL = *(const short8*)&AsL[slot * 8];
            }
            #pragma unroll
            for (int ns = 0; ns < 4; ++ns) {
                int n = ns * 16 + l15;
                int slot = n * 8 + (c ^ (n & 7));
                bH[ns] = *(const short8*)&BsH[slot * 8];
                bL[ns] = *(const short8*)&BsL[slot * 8];
            }
            #pragma unroll
            for (int ns = 0; ns < 4; ++ns)
                acc[ns] = __builtin_amdgcn_mfma_f32_16x16x32_bf16(aH, bH[ns], acc[ns], 0, 0, 0);
            #pragma unroll
            for (int ns = 0; ns < 4; ++ns)
                acc[ns] = __builtin_amdgcn_mfma_f32_16x16x32_bf16(aL, bH[ns], acc[ns], 0, 0, 0);
            #pragma unroll
            for (int ns = 0; ns < 4; ++ns)
                acc[ns] = __builtin_amdgcn_mfma_f32_16x16x32_bf16(aH, bL[ns], acc[ns], 0, 0, 0);
        }
    }

    const int rbase = rows0 + wave * 16 + quad * 4;
    #pragma unroll
    for (int ns = 0; ns < 4; ++ns) {
        int col = cols0 + ns * 16 + l15;
        #pragma unroll
        for (int r = 0; r < 4; ++r)
            C[(size_t)(rbase + r) * 256 + col] = acc[ns][r] * scale;
    }
}

// ---------------------------------------------------------------------------
// Segment flash partial v3.  Block = (b, qtile of 8, 64-key segment):
// grid 128x8, ~576 alive, LDS only ~11.5 KB (no cross-wave part buffer).
// Score phase: lane=(key=wave*16+lane>>2, ch=lane&3); k loaded in batches
// of 4 float4 (MLP=4).  eq=exp2(q) in LDS (broadcast); ek shared by 8 q.
// PV phase: wave owns q-rows {2w, 2w+1} and iterates all 64 keys with
// batched V loads — V seg is L2-resident (batches XCD-pinned via b=id%16).
// Masked keys -> s=-1e6 -> exp2 underflow to exact 0 (bit-exact skip).
// ---------------------------------------------------------------------------
__global__ __launch_bounds__(256) void score_pv_seg3(
    const float* __restrict__ qp,      // [B*NQ, H] pre-scaled by 2/ln2
    const float* __restrict__ kp,      // [B*NK, H] pre-scaled
    const float* __restrict__ values,  // [B, NK, VD]
    const int*   __restrict__ vlens,   // [B]
    const float* __restrict__ w_v,     // [H]
    float* __restrict__ pO,            // [B][8qt][8seg][8q][256]
    float* __restrict__ pM,            // [B][8qt][8seg][8q]
    float* __restrict__ pL)            // [B][8qt][8seg][8q]
{
    __shared__ float eq[8][260];
    __shared__ float wv[HD];
    __shared__ float Ps[8][68];

    const int b   = blockIdx.x & 15;    // id%8 pins batch pairs to an XCD
    const int qt  = blockIdx.x >> 4;    // 0..7
    const int seg = blockIdx.y;         // 0..7
    const int vl  = vlens[b];
    if (seg * 64 >= vl) return;

    const int t = threadIdx.x, lane = t & 63, wave = t >> 6;

    // stage eq = exp2(q) for 8 rows, and w
    const float* qsrc = qp + ((size_t)b * NQ + qt * 8) * HD;
    #pragma unroll
    for (int i = 0; i < 2; ++i) {
        int idx = i * 256 + t;
        int row = idx >> 6, c4 = (idx & 63) * 4;
        float4 v = *(const float4*)&qsrc[(size_t)row * HD + c4];
        eq[row][c4 + 0] = __builtin_amdgcn_exp2f(v.x);
        eq[row][c4 + 1] = __builtin_amdgcn_exp2f(v.y);
        eq[row][c4 + 2] = __builtin_amdgcn_exp2f(v.z);
        eq[row][c4 + 3] = __builtin_amdgcn_exp2f(v.w);
    }
    if (t < 64) *(float4*)&wv[t * 4] = *(const float4*)&w_v[t * 4];
    __syncthreads();

    // Wsum
    float Wsum;
    {
        float ws = wv[lane] + wv[lane + 64] + wv[lane + 128] + wv[lane + 192];
        #pragma unroll
        for (int off = 32; off; off >>= 1) ws += __shfl_xor(ws, off);
        Wsum = ws;
    }

    // ---- scores: batched k loads (MLP=4) ----
    const int key = wave * 16 + (lane >> 2);
    const int ch  = lane & 3;
    const int kg  = seg * 64 + key;
    const float* krow = kp + ((size_t)b * NK + kg) * HD + ch * 4;

    float s[8] = {0.f, 0.f, 0.f, 0.f, 0.f, 0.f, 0.f, 0.f};
    for (int j4 = 0; j4 < 4; ++j4) {
        float4 kk[4];
        #pragma unroll
        for (int u = 0; u < 4; ++u)
            kk[u] = *(const float4*)&krow[(j4 * 4 + u) * 16];
        #pragma unroll
        for (int u = 0; u < 4; ++u) {
            const int h = (j4 * 4 + u) * 16 + ch * 4;
            float4 w4 = *(const float4*)&wv[h];
            float ek0 = __builtin_amdgcn_exp2f(kk[u].x);
            float ek1 = __builtin_amdgcn_exp2f(kk[u].y);
            float ek2 = __builtin_amdgcn_exp2f(kk[u].z);
            float ek3 = __builtin_amdgcn_exp2f(kk[u].w);
            #pragma unroll
            for (int qi = 0; qi < 8; ++qi) {
                float4 q4 = *(const float4*)&eq[qi][h];   // LDS broadcast
                float t0 = fmaf(w4.x, __builtin_amdgcn_rcpf(fmaf(q4.x, ek0, 1.f)), s[qi]);
                t0 = fmaf(w4.y, __builtin_amdgcn_rcpf(fmaf(q4.y, ek1, 1.f)), t0);
                t0 = fmaf(w4.z, __builtin_amdgcn_rcpf(fmaf(q4.z, ek2, 1.f)), t0);
                s[qi] = fmaf(w4.w, __builtin_amdgcn_rcpf(fmaf(q4.w, ek3, 1.f)), t0);
            }
        }
    }
    #pragma unroll
    for (int qi = 0; qi < 8; ++qi) {
        s[qi] += __shfl_xor(s[qi], 1);
        s[qi] += __shfl_xor(s[qi], 2);
    }
    if (ch == 0) {
        const bool masked = (kg >= vl);
        #pragma unroll
        for (int qi = 0; qi < 8; ++qi)
            Ps[qi][key] = masked ? -1e6f : fmaf(-2.f, s[qi], Wsum);
    }
    __syncthreads();

    // ---- per-segment softmax: wave handles q rows 2w, 2w+1 ----
    const float L2E = 1.4426950408889634f;
    #pragma unroll
    for (int r = 0; r < 2; ++r) {
        const int row = wave * 2 + r;
        float sv = Ps[row][lane];
        float m = sv;
        #pragma unroll
        for (int off = 32; off; off >>= 1) m = fmaxf(m, __shfl_xor(m, off));
        float e = __builtin_amdgcn_exp2f((sv - m) * L2E);
        float l = e;
        #pragma unroll
        for (int off = 32; off; off >>= 1) l += __shfl_xor(l, off);
        Ps[row][lane] = e;
        if (lane == 0) {
            size_t mi = (((size_t)(b * 8 + qt) * 8 + seg)) * 8 + row;
            pM[mi] = m;
            pL[mi] = l;
        }
    }
    __syncthreads();

    // ---- PV: wave owns rows {2w, 2w+1}, all 64 keys, batched V loads ----
    const int r0 = wave * 2, r1 = r0 + 1;
    f32x4 acc0 = (f32x4){0.f, 0.f, 0.f, 0.f};
    f32x4 acc1 = (f32x4){0.f, 0.f, 0.f, 0.f};
    const float* vbase = values + ((size_t)b * NK + seg * 64) * HD;
    #pragma unroll 2
    for (int i0 = 0; i0 < 64; i0 += 4) {
        float4 v[4];
        #pragma unroll
        for (int u = 0; u < 4; ++u)
            v[u] = *(const float4*)&vbase[(size_t)(i0 + u) * HD + lane * 4];
        #pragma unroll
        for (int u = 0; u < 4; ++u) {
            float p0 = Ps[r0][i0 + u];
            float p1 = Ps[r1][i0 + u];
            acc0[0] = fmaf(p0, v[u].x, acc0[0]);
            acc0[1] = fmaf(p0, v[u].y, acc0[1]);
            acc0[2] = fmaf(p0, v[u].z, acc0[2]);
            acc0[3] = fmaf(p0, v[u].w, acc0[3]);
            acc1[0] = fmaf(p1, v[u].x, acc1[0]);
            acc1[1] = fmaf(p1, v[u].y, acc1[1]);
            acc1[2] = fmaf(p1, v[u].z, acc1[2]);
            acc1[3] = fmaf(p1, v[u].w, acc1[3]);
        }
    }
    const size_t ob = (((size_t)(b * 8 + qt) * 8 + seg)) * 8 * 256;
    *(f32x4*)&pO[ob + (size_t)r0 * 256 + lane * 4] = acc0;
    *(f32x4*)&pO[ob + (size_t)r1 * 256 + lane * 4] = acc1;
}

// ---------------------------------------------------------------------------
// Combine: block per (b,q), 256 threads (one vd element each).
// ---------------------------------------------------------------------------
__global__ __launch_bounds__(256) void combine_seg2(
    const float* __restrict__ pO, const float* __restrict__ pM,
    const float* __restrict__ pL, const int* __restrict__ vlens,
    float* __restrict__ out)
{
    const int b  = blockIdx.x >> 6;
    const int q  = blockIdx.x & 63;
    const int t  = threadIdx.x;
    const int vl = vlens[b];
    const int nc = (vl + 63) >> 6;
    const int qt = q >> 3, qi = q & 7;
    const float L2E = 1.4426950408889634f;

    const size_t base = (size_t)(b * 8 + qt) * 8;

    float mi[8], li[8];
    float m = -3e38f;
    #pragma unroll
    for (int i = 0; i < 8; ++i) {
        if (i < nc) {
            mi[i] = pM[(base + i) * 8 + qi];
            li[i] = pL[(base + i) * 8 + qi];
            m = fmaxf(m, mi[i]);
        }
    }
    float L = 0.f, wi[8];
    #pragma unroll
    for (int i = 0; i < 8; ++i) {
        if (i < nc) {
            wi[i] = __builtin_amdgcn_exp2f((mi[i] - m) * L2E);
            L = fmaf(li[i], wi[i], L);
        }
    }
    float acc = 0.f;
    #pragma unroll
    for (int i = 0; i < 8; ++i) {
        if (i < nc) acc = fmaf(wi[i], pO[((base + i) * 8 + qi) * 256 + t], acc);
    }
    out[((size_t)(b * 64 + q)) * 256 + t] = acc * __builtin_amdgcn_rcpf(L);
}

extern "C" void kernel_launch(void* const* d_in, const int* in_sizes, int n_in,
                              void* d_out, int out_size, void* d_ws, size_t ws_size,
                              hipStream_t stream) {
    const float* queries = (const float*)d_in[0];
    const float* keys    = (const float*)d_in[1];
    const float* values  = (const float*)d_in[2];
    const int*   vlens   = (const int*)d_in[3];
    const float* W_q     = (const float*)d_in[4];
    const float* W_k     = (const float*)d_in[5];
    const float* w_v     = (const float*)d_in[6];
    float* out = (float*)d_out;

    // ws layout (~17.5 MB of 256 MiB):
    float*  kp  = (float*)d_ws;                          // 8 MB
    float*  qp  = kp + (size_t)BB * NK * HD;             // 1 MB
    float*  pO  = qp + (size_t)BB * NQ * HD;             // 8 MB
    float*  pM  = pO + (size_t)BB * 8 * 8 * 8 * 256;     // 32 KB
    float*  pL  = pM + (size_t)BB * 8 * 8 * 8;           // 32 KB
    ushort* wqh = (ushort*)(pL + (size_t)BB * 8 * 8 * 8);
    ushort* wql = wqh + 65536;
    ushort* wkh = wql + 65536;
    ushort* wkl = wkh + 65536;

    const float SC = 2.885390081777927f;                 // 2/ln(2)

    wconv<<<dim3(128), 256, 0, stream>>>(W_q, W_k, wqh, wql, wkh, wkl);
    proj_fused<<<dim3(144, 4), 256, 0, stream>>>(queries, keys,
                                                 wqh, wql, wkh, wkl,
                                                 qp, kp, SC);
    score_pv_seg3<<<dim3(128, 8), 256, 0, stream>>>(qp, kp, values, vlens, w_v,
                                                    pO, pM, pL);
    combine_seg2<<<dim3(BB * NQ), 256, 0, stream>>>(pO, pM, pL, vlens, out);
}